// Round 4
// baseline (156.058 us; speedup 1.0000x reference)
//
#include <hip/hip_runtime.h>
#include <stdint.h>

#pragma clang fp contract(off)

#define NMS_B 8
#define NMS_N 4096
#define NMS_NW 64       // 64-bit words per suppression row
#define ROIS 256

typedef unsigned long long u64;
typedef unsigned int u32;

__device__ __forceinline__ u64 rdlane_u64(u64 v, int l) {
    u32 lo = (u32)__builtin_amdgcn_readlane((int)(u32)v, l);
    u32 hi = (u32)__builtin_amdgcn_readlane((int)(u32)(v >> 32), l);
    return ((u64)hi << 32) | lo;
}
__device__ __forceinline__ int lds_slot(int e) { return e + (e >> 2); }  // 4-way max bank aliasing

// ---------------------------------------------------------------------------
// K1a: local bitonic sort of 2048-element chunks (2 chunks/batch, 16 blocks,
// 512 thr x 4 elems). key = (~score_bits)<<32 | GLOBAL idx; direction bits
// use global e, so the result is bit-identical to the monolithic bitonic
// after its k=2048 stage. (unchanged)
// ---------------------------------------------------------------------------
__global__ __launch_bounds__(512) void nms_sort_local(
        const float* __restrict__ in, u64* __restrict__ keyb) {
    __shared__ u64 sm[2560];                   // slot(2047)=2558, 20.5 KB
    const int b = blockIdx.y, c = blockIdx.x, t = threadIdx.x;
    const int ebase = c * 2048;
    u64 key[4];

    #pragma unroll
    for (int r = 0; r < 4; ++r) {
        int e = ebase + 4 * t + r;
        float s = in[((size_t)b * NMS_N + e) * 5];
        key[r] = ((u64)(~__float_as_uint(s)) << 32) | (u32)e;
    }

    for (int k = 2; k <= 2048; k <<= 1) {
        int j = k >> 1;
        if (j >= 256) {                        // j = 1024,512,256 via LDS
            #pragma unroll
            for (int r = 0; r < 4; ++r) sm[lds_slot(4 * t + r)] = key[r];
            __syncthreads();
            for (; j >= 256; j >>= 1) {
                for (int el = t; el < 2048; el += 512) {
                    int p = el ^ j;
                    if (p > el) {
                        u64 a = sm[lds_slot(el)], cc = sm[lds_slot(p)];
                        bool up = (((ebase + el) & k) == 0);
                        if ((a > cc) == up) { sm[lds_slot(el)] = cc; sm[lds_slot(p)] = a; }
                    }
                }
                __syncthreads();
            }
            #pragma unroll
            for (int r = 0; r < 4; ++r) key[r] = sm[lds_slot(4 * t + r)];
        }
        for (; j >= 4; j >>= 1) {              // cross-lane via shfl_xor
            int d = j >> 2;
            #pragma unroll
            for (int r = 0; r < 4; ++r) {
                int e = ebase + 4 * t + r;
                u64 mine = key[r];
                u64 part = __shfl_xor(mine, d, 64);
                bool up = ((e & k) == 0);
                bool lower = ((e & j) == 0);
                u64 mn = (mine < part) ? mine : part;
                u64 mx = (mine < part) ? part : mine;
                key[r] = (up == lower) ? mn : mx;
            }
        }
        for (; j >= 1; j >>= 1) {              // j in {2,1}: in-thread
            #pragma unroll
            for (int r = 0; r < 4; ++r) {
                int pr = r | j;
                if (((r & j) == 0) && pr < 4) {
                    int e = ebase + 4 * t + r;
                    bool up = ((e & k) == 0);
                    u64 a = key[r], cc = key[pr];
                    if ((a > cc) == up) { key[r] = cc; key[pr] = a; }
                }
            }
        }
    }

    #pragma unroll
    for (int r = 0; r < 4; ++r)
        keyb[(size_t)b * NMS_N + ebase + 4 * t + r] = key[r];
}

// ---------------------------------------------------------------------------
// K1b: merge stage k=4096 at 2x block parallelism (all-ascending at k=4096,
// j=2048 substage computed redundantly from read-only keyb). 16 blocks x
// 512 thr, 20.5 KB LDS. Bit-identical network. Epilogue: sorted idx +
// corners (floor(w/2) per reference) + HALF-areas (exact). (unchanged)
// ---------------------------------------------------------------------------
__global__ __launch_bounds__(512) void nms_sort_merge(
        const float* __restrict__ in, const u64* __restrict__ keyb,
        u32* __restrict__ sortedIdx, float4* __restrict__ crn,
        float* __restrict__ ha) {
    __shared__ u64 sm[2560];                   // slot(2047)=2558, 20.5 KB
    const int b = blockIdx.y, c = blockIdx.x, t = threadIdx.x;
    const int ebase = c * 2048;
    u64 key[4];

    #pragma unroll
    for (int r = 0; r < 4; ++r) {
        int el = 4 * t + r;
        u64 mine = keyb[(size_t)b * NMS_N + ebase + el];
        u64 part = keyb[(size_t)b * NMS_N + (ebase ^ 2048) + el];
        u64 mn = mine < part ? mine : part;
        u64 mx = mine < part ? part : mine;
        key[r] = (c == 0) ? mn : mx;
    }

    #pragma unroll
    for (int r = 0; r < 4; ++r) sm[lds_slot(4 * t + r)] = key[r];
    __syncthreads();
    for (int j = 1024; j >= 256; j >>= 1) {
        for (int el = t; el < 2048; el += 512) {
            int p = el ^ j;
            if (p > el) {
                u64 a = sm[lds_slot(el)], cc = sm[lds_slot(p)];
                if (a > cc) { sm[lds_slot(el)] = cc; sm[lds_slot(p)] = a; }
            }
        }
        __syncthreads();
    }
    #pragma unroll
    for (int r = 0; r < 4; ++r) key[r] = sm[lds_slot(4 * t + r)];

    for (int j = 128; j >= 4; j >>= 1) {       // cross-lane via shfl_xor
        int d = j >> 2;
        #pragma unroll
        for (int r = 0; r < 4; ++r) {
            int el = 4 * t + r;
            u64 mine = key[r];
            u64 part = __shfl_xor(mine, d, 64);
            bool lower = ((el & j) == 0);
            u64 mn = (mine < part) ? mine : part;
            u64 mx = (mine < part) ? part : mine;
            key[r] = lower ? mn : mx;
        }
    }
    for (int j = 2; j >= 1; j >>= 1) {         // j in {2,1}: in-thread
        #pragma unroll
        for (int r = 0; r < 4; ++r) {
            int pr = r | j;
            if (((r & j) == 0) && pr < 4) {
                u64 a = key[r], cc = key[pr];
                if (a > cc) { key[r] = cc; key[pr] = a; }
            }
        }
    }

    #pragma unroll
    for (int r = 0; r < 4; ++r) {
        int e = ebase + 4 * t + r;
        u32 orig = (u32)key[r];
        const float* bp = in + ((size_t)b * NMS_N + orig) * 5;
        float x = bp[1], y = bp[2], w = bp[3], h = bp[4];
        float ws_ = floorf(w * 0.5f);
        float hs_ = floorf(h * 0.5f);
        float X1 = x - ws_, Y1 = y - hs_, X2 = x + ws_, Y2 = y + hs_;
        size_t g = (size_t)b * NMS_N + e;
        sortedIdx[g] = orig;
        crn[g] = make_float4(X1, Y1, X2, Y2);
        ha[g] = 0.5f * ((X2 - X1) * (Y2 - Y1));   // exact: area is a small int
    }
}

// ---------------------------------------------------------------------------
// K2: suppression bitmask, ballot orientation, equal-work trapezoid grid.
// Diagonal units also write the dense diag array diagw2. (unchanged)
// ---------------------------------------------------------------------------
__global__ __launch_bounds__(256) void nms_mask(
        const float4* __restrict__ crn, const float* __restrict__ ha,
        u64* __restrict__ mask, u64* __restrict__ diagw2) {
    const int b = blockIdx.y;
    const int u = blockIdx.x * 4 + (threadIdx.x >> 6);   // unit id, 0..1055
    const int lane = threadIdx.x & 63;

    int wp = (int)sqrtf((float)u);
    while (wp * (wp + 1) > u) --wp;
    while ((wp + 1) * (wp + 2) <= u) ++wp;
    const int rowblk = u - wp * (wp + 1);                // 0..2*wp+1

    const size_t base = (size_t)b * NMS_N;
    const int c0 = wp * 128 + lane;
    float4 c0c = crn[base + c0];
    float4 c1c = crn[base + c0 + 64];
    float h0 = ha[base + c0];
    float h1 = ha[base + c0 + 64];

    const int rowbase = __builtin_amdgcn_readfirstlane(rowblk * 64);
    const float4* rowc = crn + base + rowbase;
    const float* rowh = ha + base + rowbase;

    u64 w0 = 0, w1 = 0;
    for (int rg = 0; rg < 64; rg += 8) {
        float fx1[8], fy1[8], fx2[8], fy2[8], fha[8];
        #pragma unroll
        for (int q = 0; q < 8; ++q) {                    // uniform -> s_load
            float4 rc = rowc[rg + q];
            fx1[q] = rc.x; fy1[q] = rc.y; fx2[q] = rc.z; fy2[q] = rc.w;
            fha[q] = rowh[rg + q];
        }
        #pragma unroll
        for (int q = 0; q < 8; ++q) {
            float iw0 = fmaxf(fminf(fx2[q], c0c.z) - fmaxf(fx1[q], c0c.x), 0.0f);
            float ih0 = fmaxf(fminf(fy2[q], c0c.w) - fmaxf(fy1[q], c0c.y), 0.0f);
            float in0 = iw0 * ih0;
            bool p0 = in0 > fmaf(-0.5f, in0, fha[q] + h0);

            float iw1 = fmaxf(fminf(fx2[q], c1c.z) - fmaxf(fx1[q], c1c.x), 0.0f);
            float ih1 = fmaxf(fminf(fy2[q], c1c.w) - fmaxf(fy1[q], c1c.y), 0.0f);
            float in1 = iw1 * ih1;
            bool p1 = in1 > fmaf(-0.5f, in1, fha[q] + h1);

            u64 b0 = __ballot(p0);
            u64 b1 = __ballot(p1);
            if (lane == rg + q) { w0 = b0; w1 = b1; }
        }
    }

    ulonglong2 v; v.x = w0; v.y = w1;
    *(ulonglong2*)&mask[(base + rowbase + lane) * NMS_NW + wp * 2] = v;

    if (rowblk == 2 * wp || rowblk == 2 * wp + 1) {      // diagonal unit
        int r = ((rowblk & 1) << 6) + lane;              // row offset in 128-window
        *(ulonglong2*)&diagw2[(((size_t)b * 32 + wp) * 128 + r) * 2] = v;
    }
}

// ---------------------------------------------------------------------------
// K3 v6: BALLOT SCAN. v4/v5 post-mortem: wait-count fixes bought only ~6 us
// of 40 -> the serial per-kept readlane chain (~250-300cy x 256 kept) was
// the real cost. v6 exploits IoU SYMMETRY: "kept row r suppresses row l"
// == bit r of row l's OWN diag word, which lane l holds in registers. Each
// kept step is now: all lanes test bit r of their dLo/dHi (uniform shift),
// update a per-lane avail flag, __ballot rebuilds the avail word. Dependent
// chain per kept: ballot -> ctz -> shift/and -> ballot (~4 ops). Backward
// bits harmless (monotone scan); explicit lane!=r clear preserves the
// zero-area self-IoU edge case exactly. kb bitmaps + v5 batched mask-row
// loads into supp unchanged. Bit-identical kept sequence.
// ---------------------------------------------------------------------------
__global__ __launch_bounds__(64, 1) void nms_scan(
        const float* __restrict__ in, const u64* __restrict__ mask,
        const u64* __restrict__ diagw2, const u32* __restrict__ sortedIdx,
        float* __restrict__ outp) {
    const int b = blockIdx.x, lane = threadIdx.x;
    const u64* M = mask + (size_t)b * NMS_N * NMS_NW;
    const u64* D = diagw2 + (size_t)b * 32 * 128 * 2;

    __shared__ int kept[ROIS];
    for (int r = lane; r < ROIS; r += 64) kept[r] = 0;   // safety fallback

    int count = 0;
    u64 supp = 0;        // lane l owns suppressed word l (cols 64l..64l+63)

    // diag for window 0: lane holds row `lane` (dLo0,dLo1 = words 2Wp,2Wp+1)
    // and row `64+lane` (dHi0,dHi1).
    u64 dLo0, dLo1, dHi0, dHi1;
    {
        ulonglong2 tl = *(const ulonglong2*)&D[(size_t)lane * 2];
        ulonglong2 th = *(const ulonglong2*)&D[(size_t)(64 + lane) * 2];
        dLo0 = tl.x; dLo1 = tl.y; dHi0 = th.x; dHi1 = th.y;
    }

    for (int Wp = 0; Wp < 32 && count < ROIS; ++Wp) {
        // prefetch next window's diagonal block (in flight during scan)
        u64 nLo0 = 0, nLo1 = 0, nHi0 = 0, nHi1 = 0;
        if (Wp + 1 < 32) {
            const u64* Dn = D + (size_t)(Wp + 1) * 128 * 2;
            ulonglong2 tl = *(const ulonglong2*)&Dn[(size_t)lane * 2];
            ulonglong2 th = *(const ulonglong2*)&Dn[(size_t)(64 + lane) * 2];
            nLo0 = tl.x; nLo1 = tl.y; nHi0 = th.x; nHi1 = th.y;
        }

        // per-lane availability flags for rows lane (lo) and 64+lane (hi)
        u64 suppLo = rdlane_u64(supp, 2 * Wp);
        u64 suppHi = rdlane_u64(supp, 2 * Wp + 1);
        int fLo = (int)((suppLo >> lane) & 1ULL) ^ 1;
        int fHi = (int)((suppHi >> lane) & 1ULL) ^ 1;
        u64 kbLo = 0, kbHi = 0;

        // ---- lo half: rows Wp*128 + [0,64) ----
        u64 availLo = __ballot(fLo != 0);
        while (availLo != 0 && count < ROIS) {
            int r = __builtin_ctzll(availLo);          // uniform
            if (lane == 0) kept[count] = Wp * 128 + r;
            ++count;
            kbLo |= (1ULL << r);
            // symmetry: bit r of row l's word == kept r suppresses row l
            fLo &= ((int)((dLo0 >> r) & 1ULL) ^ 1) & (int)(lane != r);
            fHi &= ((int)((dHi0 >> r) & 1ULL) ^ 1);
            availLo = __ballot(fLo != 0);
        }
        // ---- hi half: rows Wp*128 + [64,128) ----
        u64 availHi = __ballot(fHi != 0);
        while (availHi != 0 && count < ROIS) {
            int r = __builtin_ctzll(availHi);          // local idx in hi half
            if (lane == 0) kept[count] = Wp * 128 + 64 + r;
            ++count;
            kbHi |= (1ULL << r);
            fHi &= ((int)((dHi1 >> r) & 1ULL) ^ 1) & (int)(lane != r);
            availHi = __ballot(fHi != 0);
        }

        if (count >= ROIS) break;              // no future windows -> no update

        // ---- batched OR of kept rows' mask rows: 16 loads forced in flight ----
        if ((kbLo | kbHi) != 0) {
            u64 kb0 = kbLo, kb1 = kbHi;
            const int rbase = Wp * 128;
            const int rfirst = (kb0 != 0) ? __builtin_ctzll(kb0)
                                          : 64 + __builtin_ctzll(kb1);
            while ((kb0 | kb1) != 0) {
                int idx[16];
                #pragma unroll
                for (int i = 0; i < 16; ++i) {
                    int r = rfirst;            // pad with first kept (idempotent)
                    if (kb0 != 0)      { r = __builtin_ctzll(kb0); kb0 &= kb0 - 1; }
                    else if (kb1 != 0) { r = 64 + __builtin_ctzll(kb1); kb1 &= kb1 - 1; }
                    idx[i] = r;
                }
                u64 v0  = M[(size_t)(rbase + idx[0])  * NMS_NW + lane];
                u64 v1  = M[(size_t)(rbase + idx[1])  * NMS_NW + lane];
                u64 v2  = M[(size_t)(rbase + idx[2])  * NMS_NW + lane];
                u64 v3  = M[(size_t)(rbase + idx[3])  * NMS_NW + lane];
                u64 v4  = M[(size_t)(rbase + idx[4])  * NMS_NW + lane];
                u64 v5  = M[(size_t)(rbase + idx[5])  * NMS_NW + lane];
                u64 v6  = M[(size_t)(rbase + idx[6])  * NMS_NW + lane];
                u64 v7  = M[(size_t)(rbase + idx[7])  * NMS_NW + lane];
                u64 v8  = M[(size_t)(rbase + idx[8])  * NMS_NW + lane];
                u64 v9  = M[(size_t)(rbase + idx[9])  * NMS_NW + lane];
                u64 v10 = M[(size_t)(rbase + idx[10]) * NMS_NW + lane];
                u64 v11 = M[(size_t)(rbase + idx[11]) * NMS_NW + lane];
                u64 v12 = M[(size_t)(rbase + idx[12]) * NMS_NW + lane];
                u64 v13 = M[(size_t)(rbase + idx[13]) * NMS_NW + lane];
                u64 v14 = M[(size_t)(rbase + idx[14]) * NMS_NW + lane];
                u64 v15 = M[(size_t)(rbase + idx[15]) * NMS_NW + lane];
                asm volatile("" : "+v"(v0), "+v"(v1), "+v"(v2),  "+v"(v3),
                                  "+v"(v4), "+v"(v5), "+v"(v6),  "+v"(v7),
                                  "+v"(v8), "+v"(v9), "+v"(v10), "+v"(v11),
                                  "+v"(v12), "+v"(v13), "+v"(v14), "+v"(v15));
                supp |= ((v0 | v1) | (v2 | v3)) | ((v4 | v5) | (v6 | v7))
                      | ((v8 | v9) | (v10 | v11)) | ((v12 | v13) | (v14 | v15));
            }
        }

        dLo0 = nLo0; dLo1 = nLo1; dHi0 = nHi0; dHi1 = nHi1;
    }

    __syncthreads();
    for (int r = lane; r < ROIS; r += 64) {
        int pos = kept[r];
        int orig = (int)sortedIdx[(size_t)b * NMS_N + pos];
        const float* bp = in + ((size_t)b * NMS_N + orig) * 5;
        float4 o = make_float4(bp[1], bp[2], bp[3], bp[4]);
        ((float4*)outp)[(size_t)b * ROIS + r] = o;
    }
}

extern "C" void kernel_launch(void* const* d_in, const int* in_sizes, int n_in,
                              void* d_out, int out_size, void* d_ws, size_t ws_size,
                              hipStream_t stream) {
    const float* in = (const float*)d_in[0];
    float* out = (float*)d_out;
    char* ws = (char*)d_ws;

    u64* mask = (u64*)ws;                                          // 16 MB
    size_t off = (size_t)NMS_B * NMS_N * NMS_NW * sizeof(u64);
    u32* sortedIdx = (u32*)(ws + off); off += (size_t)NMS_B * NMS_N * 4;
    float4* crn = (float4*)(ws + off); off += (size_t)NMS_B * NMS_N * 16;
    float* ha = (float*)(ws + off);    off += (size_t)NMS_B * NMS_N * 4;
    u64* keyb = (u64*)(ws + off);      off += (size_t)NMS_B * NMS_N * 8;
    u64* diagw2 = (u64*)(ws + off);    off += (size_t)NMS_B * 32 * 128 * 2 * 8;

    nms_sort_local<<<dim3(2, NMS_B), 512, 0, stream>>>(in, keyb);
    nms_sort_merge<<<dim3(2, NMS_B), 512, 0, stream>>>(in, keyb, sortedIdx, crn, ha);
    nms_mask<<<dim3(264, NMS_B), 256, 0, stream>>>(crn, ha, mask, diagw2);
    nms_scan<<<NMS_B, 64, 0, stream>>>(in, mask, diagw2, sortedIdx, out);
}

// Round 5
// 138.039 us; speedup vs baseline: 1.1305x; 1.1305x over previous
//
#include <hip/hip_runtime.h>
#include <stdint.h>

#pragma clang fp contract(off)

#define NMS_B 8
#define NMS_N 4096
#define ROIS 256

typedef unsigned long long u64;
typedef unsigned int u32;

__device__ __forceinline__ int lds_slot(int e) { return e + (e >> 2); }  // 4-way max bank aliasing

// ---------------------------------------------------------------------------
// K1a: local bitonic sort of 2048-element chunks (2 chunks/batch, 16 blocks,
// 512 thr x 4 elems). key = (~score_bits)<<32 | GLOBAL idx. (unchanged)
// ---------------------------------------------------------------------------
__global__ __launch_bounds__(512) void nms_sort_local(
        const float* __restrict__ in, u64* __restrict__ keyb) {
    __shared__ u64 sm[2560];                   // slot(2047)=2558, 20.5 KB
    const int b = blockIdx.y, c = blockIdx.x, t = threadIdx.x;
    const int ebase = c * 2048;
    u64 key[4];

    #pragma unroll
    for (int r = 0; r < 4; ++r) {
        int e = ebase + 4 * t + r;
        float s = in[((size_t)b * NMS_N + e) * 5];
        key[r] = ((u64)(~__float_as_uint(s)) << 32) | (u32)e;
    }

    for (int k = 2; k <= 2048; k <<= 1) {
        int j = k >> 1;
        if (j >= 256) {                        // j = 1024,512,256 via LDS
            #pragma unroll
            for (int r = 0; r < 4; ++r) sm[lds_slot(4 * t + r)] = key[r];
            __syncthreads();
            for (; j >= 256; j >>= 1) {
                for (int el = t; el < 2048; el += 512) {
                    int p = el ^ j;
                    if (p > el) {
                        u64 a = sm[lds_slot(el)], cc = sm[lds_slot(p)];
                        bool up = (((ebase + el) & k) == 0);
                        if ((a > cc) == up) { sm[lds_slot(el)] = cc; sm[lds_slot(p)] = a; }
                    }
                }
                __syncthreads();
            }
            #pragma unroll
            for (int r = 0; r < 4; ++r) key[r] = sm[lds_slot(4 * t + r)];
        }
        for (; j >= 4; j >>= 1) {              // cross-lane via shfl_xor
            int d = j >> 2;
            #pragma unroll
            for (int r = 0; r < 4; ++r) {
                int e = ebase + 4 * t + r;
                u64 mine = key[r];
                u64 part = __shfl_xor(mine, d, 64);
                bool up = ((e & k) == 0);
                bool lower = ((e & j) == 0);
                u64 mn = (mine < part) ? mine : part;
                u64 mx = (mine < part) ? part : mine;
                key[r] = (up == lower) ? mn : mx;
            }
        }
        for (; j >= 1; j >>= 1) {              // j in {2,1}: in-thread
            #pragma unroll
            for (int r = 0; r < 4; ++r) {
                int pr = r | j;
                if (((r & j) == 0) && pr < 4) {
                    int e = ebase + 4 * t + r;
                    bool up = ((e & k) == 0);
                    u64 a = key[r], cc = key[pr];
                    if ((a > cc) == up) { key[r] = cc; key[pr] = a; }
                }
            }
        }
    }

    #pragma unroll
    for (int r = 0; r < 4; ++r)
        keyb[(size_t)b * NMS_N + ebase + 4 * t + r] = key[r];
}

// ---------------------------------------------------------------------------
// K1b: merge stage k=4096 at 2x block parallelism. Epilogue: sorted idx +
// corners + HALF-areas. (unchanged)
// ---------------------------------------------------------------------------
__global__ __launch_bounds__(512) void nms_sort_merge(
        const float* __restrict__ in, const u64* __restrict__ keyb,
        u32* __restrict__ sortedIdx, float4* __restrict__ crn,
        float* __restrict__ ha) {
    __shared__ u64 sm[2560];                   // slot(2047)=2558, 20.5 KB
    const int b = blockIdx.y, c = blockIdx.x, t = threadIdx.x;
    const int ebase = c * 2048;
    u64 key[4];

    #pragma unroll
    for (int r = 0; r < 4; ++r) {
        int el = 4 * t + r;
        u64 mine = keyb[(size_t)b * NMS_N + ebase + el];
        u64 part = keyb[(size_t)b * NMS_N + (ebase ^ 2048) + el];
        u64 mn = mine < part ? mine : part;
        u64 mx = mine < part ? part : mine;
        key[r] = (c == 0) ? mn : mx;
    }

    #pragma unroll
    for (int r = 0; r < 4; ++r) sm[lds_slot(4 * t + r)] = key[r];
    __syncthreads();
    for (int j = 1024; j >= 256; j >>= 1) {
        for (int el = t; el < 2048; el += 512) {
            int p = el ^ j;
            if (p > el) {
                u64 a = sm[lds_slot(el)], cc = sm[lds_slot(p)];
                if (a > cc) { sm[lds_slot(el)] = cc; sm[lds_slot(p)] = a; }
            }
        }
        __syncthreads();
    }
    #pragma unroll
    for (int r = 0; r < 4; ++r) key[r] = sm[lds_slot(4 * t + r)];

    for (int j = 128; j >= 4; j >>= 1) {       // cross-lane via shfl_xor
        int d = j >> 2;
        #pragma unroll
        for (int r = 0; r < 4; ++r) {
            int el = 4 * t + r;
            u64 mine = key[r];
            u64 part = __shfl_xor(mine, d, 64);
            bool lower = ((el & j) == 0);
            u64 mn = (mine < part) ? mine : part;
            u64 mx = (mine < part) ? part : mine;
            key[r] = lower ? mn : mx;
        }
    }
    for (int j = 2; j >= 1; j >>= 1) {         // j in {2,1}: in-thread
        #pragma unroll
        for (int r = 0; r < 4; ++r) {
            int pr = r | j;
            if (((r & j) == 0) && pr < 4) {
                u64 a = key[r], cc = key[pr];
                if (a > cc) { key[r] = cc; key[pr] = a; }
            }
        }
    }

    #pragma unroll
    for (int r = 0; r < 4; ++r) {
        int e = ebase + 4 * t + r;
        u32 orig = (u32)key[r];
        const float* bp = in + ((size_t)b * NMS_N + orig) * 5;
        float x = bp[1], y = bp[2], w = bp[3], h = bp[4];
        float ws_ = floorf(w * 0.5f);
        float hs_ = floorf(h * 0.5f);
        float X1 = x - ws_, Y1 = y - hs_, X2 = x + ws_, Y2 = y + hs_;
        size_t g = (size_t)b * NMS_N + e;
        sortedIdx[g] = orig;
        crn[g] = make_float4(X1, Y1, X2, Y2);
        ha[g] = 0.5f * ((X2 - X1) * (Y2 - Y1));   // exact: area is a small int
    }
}

// ---------------------------------------------------------------------------
// K2 v2: TRANSPOSED mask. Each lane owns columns c0=wp*128+lane, c1=c0+64
// and accumulates COLUMN words t0/t1 locally (bit row = predicate) instead
// of ballot-ing row words. maskT[w][c] bit j = "row 64w+j suppresses col c",
// layout word-major [64][4096] per batch -> lane stores fully coalesced.
// No ballots, no diagw2, no row-mask. IoU arithmetic byte-identical.
// ---------------------------------------------------------------------------
__global__ __launch_bounds__(256) void nms_mask(
        const float4* __restrict__ crn, const float* __restrict__ ha,
        u64* __restrict__ maskT) {
    const int b = blockIdx.y;
    const int u = blockIdx.x * 4 + (threadIdx.x >> 6);   // unit id, 0..1055
    const int lane = threadIdx.x & 63;

    int wp = (int)sqrtf((float)u);
    while (wp * (wp + 1) > u) --wp;
    while ((wp + 1) * (wp + 2) <= u) ++wp;
    const int rowblk = u - wp * (wp + 1);                // 0..2*wp+1

    const size_t base = (size_t)b * NMS_N;
    const int c0 = wp * 128 + lane;
    float4 c0c = crn[base + c0];
    float4 c1c = crn[base + c0 + 64];
    float h0 = ha[base + c0];
    float h1 = ha[base + c0 + 64];

    const int rowbase = __builtin_amdgcn_readfirstlane(rowblk * 64);
    const float4* rowc = crn + base + rowbase;
    const float* rowh = ha + base + rowbase;

    u64 t0 = 0, t1 = 0;
    for (int rg = 0; rg < 64; rg += 8) {
        float fx1[8], fy1[8], fx2[8], fy2[8], fha[8];
        #pragma unroll
        for (int q = 0; q < 8; ++q) {                    // uniform -> s_load
            float4 rc = rowc[rg + q];
            fx1[q] = rc.x; fy1[q] = rc.y; fx2[q] = rc.z; fy2[q] = rc.w;
            fha[q] = rowh[rg + q];
        }
        #pragma unroll
        for (int q = 0; q < 8; ++q) {
            float iw0 = fmaxf(fminf(fx2[q], c0c.z) - fmaxf(fx1[q], c0c.x), 0.0f);
            float ih0 = fmaxf(fminf(fy2[q], c0c.w) - fmaxf(fy1[q], c0c.y), 0.0f);
            float in0 = iw0 * ih0;
            bool p0 = in0 > fmaf(-0.5f, in0, fha[q] + h0);

            float iw1 = fmaxf(fminf(fx2[q], c1c.z) - fmaxf(fx1[q], c1c.x), 0.0f);
            float ih1 = fmaxf(fminf(fy2[q], c1c.w) - fmaxf(fy1[q], c1c.y), 0.0f);
            float in1 = iw1 * ih1;
            bool p1 = in1 > fmaf(-0.5f, in1, fha[q] + h1);

            t0 |= ((u64)(p0 ? 1u : 0u)) << (rg + q);     // bit = row rowbase+rg+q
            t1 |= ((u64)(p1 ? 1u : 0u)) << (rg + q);
        }
    }

    u64* Tb = maskT + (size_t)b * 64 * 4096;
    Tb[(size_t)rowblk * 4096 + c0]      = t0;            // coalesced across lanes
    Tb[(size_t)rowblk * 4096 + c0 + 64] = t1;
}

// ---------------------------------------------------------------------------
// K3 v7: column-oriented scan, ZERO dependent-address loads. Rows 0..511:
// all 36 lower-triangle suppressor words (T[w][64k+lane], w<=k<8) loaded
// upfront into registers (static addresses, one cold round-trip). Scan =
// pure ballot chain; kept-history propagates via register kb words applied
// at group boundaries (deferred cross-group update). Columns beyond 512
// (only if <256 kept in first 512 — input-dependent correctness path):
// generic 128-row windows with LDS Khist history.
// Rationale: v3-v6 all ~40us regardless of chain/wait structure -> the
// invariant dependent mask-row gathers were the suspect; v7 removes them.
// ---------------------------------------------------------------------------
__global__ __launch_bounds__(64, 1) void nms_scan(
        const float* __restrict__ in, const u64* __restrict__ maskT,
        const u32* __restrict__ sortedIdx, float* __restrict__ outp) {
    const int b = blockIdx.x, lane = threadIdx.x;
    const u64* T = maskT + (size_t)b * 64 * 4096;

    __shared__ u64 Khist[64];
    __shared__ int kept[ROIS];
    for (int r = lane; r < ROIS; r += 64) kept[r] = 0;   // safety fallback

    int count = 0;

    // ---- fast block: rows/cols [0,512). h[k][w] = T[w][64k+lane] ----
    u64 h[8][8];
    #pragma unroll
    for (int k = 0; k < 8; ++k) {
        #pragma unroll
        for (int w = 0; w <= k; ++w)
            h[k][w] = T[(size_t)w * 4096 + 64 * k + lane];
    }

    u32 f[8];
    #pragma unroll
    for (int k = 0; k < 8; ++k) f[k] = 1u;

    u64 kbv[8];
    #pragma unroll
    for (int g = 0; g < 8; ++g) kbv[g] = 0;

    bool done = false;
    #pragma unroll
    for (int g = 0; g < 8; ++g) {
        if (!done) {
            u64 kb = 0;
            u64 avail = __ballot(f[g] != 0);
            while (avail != 0 && count < ROIS) {
                int r = __builtin_ctzll(avail);          // wave-uniform
                if (lane == 0) kept[count] = g * 64 + r;
                ++count;
                kb |= 1ULL << r;
                // in-group: kept r suppresses row `lane` via bit r of its
                // own column word; kept row removes itself (lane != r).
                u32 bit = (u32)(h[g][g] >> r) & 1u;
                f[g] &= (bit ^ 1u) & (u32)(lane != r);
                avail = __ballot(f[g] != 0);
            }
            kbv[g] = kb;
            if (count >= ROIS) {
                done = true;
            } else {
                // deferred: apply this group's kept set to later groups
                #pragma unroll
                for (int k2 = g + 1; k2 < 8; ++k2)
                    f[k2] &= (u32)((h[k2][g] & kb) == 0);
            }
        }
    }

    // ---- generic continuation (correctness path; rarely/never runs) ----
    if (count < ROIS) {
        if (lane == 0) {
            #pragma unroll
            for (int g = 0; g < 8; ++g) Khist[g] = kbv[g];
        }
        for (int Wp = 4; Wp < 32 && count < ROIS; ++Wp) {
            const int cLo = 128 * Wp + lane, cHi = cLo + 64;
            u64 curLo0 = T[(size_t)(2 * Wp) * 4096 + cLo];
            u64 curHi0 = T[(size_t)(2 * Wp) * 4096 + cHi];
            u64 curHi1 = T[(size_t)(2 * Wp + 1) * 4096 + cHi];
            u32 fLo = 1u, fHi = 1u;
            for (int w = 0; w < 2 * Wp; ++w) {           // history vs kept words
                u64 kw = Khist[w];
                fLo &= (u32)((T[(size_t)w * 4096 + cLo] & kw) == 0);
                fHi &= (u32)((T[(size_t)w * 4096 + cHi] & kw) == 0);
            }
            u64 kbLo = 0, kbHi = 0;
            u64 availLo = __ballot(fLo != 0);
            while (availLo != 0 && count < ROIS) {
                int r = __builtin_ctzll(availLo);
                if (lane == 0) kept[count] = Wp * 128 + r;
                ++count;
                kbLo |= 1ULL << r;
                fLo &= (u32)(((curLo0 >> r) & 1ULL) ^ 1ULL) & (u32)(lane != r);
                fHi &= (u32)(((curHi0 >> r) & 1ULL) ^ 1ULL);
                availLo = __ballot(fLo != 0);
            }
            u64 availHi = __ballot(fHi != 0);
            while (availHi != 0 && count < ROIS) {
                int r = __builtin_ctzll(availHi);
                if (lane == 0) kept[count] = Wp * 128 + 64 + r;
                ++count;
                kbHi |= 1ULL << r;
                fHi &= (u32)(((curHi1 >> r) & 1ULL) ^ 1ULL) & (u32)(lane != r);
                availHi = __ballot(fHi != 0);
            }
            if (lane == 0) { Khist[2 * Wp] = kbLo; Khist[2 * Wp + 1] = kbHi; }
        }
    }

    __syncthreads();
    for (int r = lane; r < ROIS; r += 64) {
        int pos = kept[r];
        int orig = (int)sortedIdx[(size_t)b * NMS_N + pos];
        const float* bp = in + ((size_t)b * NMS_N + orig) * 5;
        float4 o = make_float4(bp[1], bp[2], bp[3], bp[4]);
        ((float4*)outp)[(size_t)b * ROIS + r] = o;
    }
}

extern "C" void kernel_launch(void* const* d_in, const int* in_sizes, int n_in,
                              void* d_out, int out_size, void* d_ws, size_t ws_size,
                              hipStream_t stream) {
    const float* in = (const float*)d_in[0];
    float* out = (float*)d_out;
    char* ws = (char*)d_ws;

    u64* maskT = (u64*)ws;                                         // 16 MB
    size_t off = (size_t)NMS_B * 64 * 4096 * sizeof(u64);
    u32* sortedIdx = (u32*)(ws + off); off += (size_t)NMS_B * NMS_N * 4;
    float4* crn = (float4*)(ws + off); off += (size_t)NMS_B * NMS_N * 16;
    float* ha = (float*)(ws + off);    off += (size_t)NMS_B * NMS_N * 4;
    u64* keyb = (u64*)(ws + off);      off += (size_t)NMS_B * NMS_N * 8;

    nms_sort_local<<<dim3(2, NMS_B), 512, 0, stream>>>(in, keyb);
    nms_sort_merge<<<dim3(2, NMS_B), 512, 0, stream>>>(in, keyb, sortedIdx, crn, ha);
    nms_mask<<<dim3(264, NMS_B), 256, 0, stream>>>(crn, ha, maskT);
    nms_scan<<<NMS_B, 64, 0, stream>>>(in, maskT, sortedIdx, out);
}

// Round 6
// 130.021 us; speedup vs baseline: 1.2003x; 1.0617x over previous
//
#include <hip/hip_runtime.h>
#include <stdint.h>

#pragma clang fp contract(off)

#define NMS_B 8
#define NMS_N 4096
#define ROIS 256

typedef unsigned long long u64;
typedef unsigned int u32;

__device__ __forceinline__ int lds_slot(int e) { return e + (e >> 2); }  // 4-way max bank aliasing

// suppression predicate, EXACT operand order of the proven K2:
// row box (rc,rh) vs col box (cc,ch); true => row suppresses col (IoU > 0.5)
__device__ __forceinline__ bool sup_pred(float4 rc, float rh, float4 cc, float ch) {
    float iw = fmaxf(fminf(rc.z, cc.z) - fmaxf(rc.x, cc.x), 0.0f);
    float ih = fmaxf(fminf(rc.w, cc.w) - fmaxf(rc.y, cc.y), 0.0f);
    float inter = iw * ih;
    return inter > fmaf(-0.5f, inter, rh + ch);   // 1.5*inter > haR+haC
}

// ---------------------------------------------------------------------------
// v8: ONE kernel, one block per batch (8 x 1024).
//   P1 sort:   full bitonic (K1a's proven network, 1024 thr x 4 elems,
//              k=2..4096, direction by global e) entirely in-block.
//   P2 corners: per-elem corners/half-areas; all 4096 -> global (tail+output),
//              first 512 also -> LDS (aliased over the dead sort arena).
//   P3 h-block: 36 lower-triangle suppressor words (cols 64k+lane vs rows
//              64w..64w+63), computed from LDS boxes by 16 waves. This
//              replaces ALL of K2 (3% of its pair count, 0 of its 16 MB).
//   P4 scan:   wave 0, v7's ballot chain (h from LDS).
//   P5 tail:   correctness-only (count<256 after 512 rows): on-the-fly IoU
//              vs kept list + in-window words. Never runs on bench data
//              (v7 evidence: fast block satisfies ROIS).
//   P6 output: 256-thread gather.
// Rationale: 5 rounds of K3-only edits left a 114us invariant baseline =
// K1a+K1b+K2+4 launches. The scan consumes only the 512x512 corner of K2's
// 4096x4096 work -> fuse and compute exactly what's needed.
// ---------------------------------------------------------------------------
__global__ __launch_bounds__(1024, 1) void nms_all(
        const float* __restrict__ in, u32* __restrict__ sortedIdx,
        float4* __restrict__ crn, float* __restrict__ ha,
        float* __restrict__ outp) {
    __shared__ u64 sm[5120];                 // sort arena 41KB; aliased after
    __shared__ int kept[ROIS];
    const int b = blockIdx.x, t = threadIdx.x;
    const int lane = t & 63, wid = t >> 6;
    const size_t base = (size_t)b * NMS_N;

    // ---- P1: bitonic sort, 4096 elems, 4/thread ----
    u64 key[4];
    #pragma unroll
    for (int r = 0; r < 4; ++r) {
        int e = 4 * t + r;
        float s = in[(base + e) * 5];
        key[r] = ((u64)(~__float_as_uint(s)) << 32) | (u32)e;
    }

    for (int k = 2; k <= 4096; k <<= 1) {
        int j = k >> 1;
        if (j >= 256) {                      // j = 2048,1024,512,256 via LDS
            #pragma unroll
            for (int r = 0; r < 4; ++r) sm[lds_slot(4 * t + r)] = key[r];
            __syncthreads();
            for (; j >= 256; j >>= 1) {
                for (int el = t; el < 4096; el += 1024) {
                    int p = el ^ j;
                    if (p > el) {
                        u64 a = sm[lds_slot(el)], cc = sm[lds_slot(p)];
                        bool up = ((el & k) == 0);
                        if ((a > cc) == up) { sm[lds_slot(el)] = cc; sm[lds_slot(p)] = a; }
                    }
                }
                __syncthreads();
            }
            #pragma unroll
            for (int r = 0; r < 4; ++r) key[r] = sm[lds_slot(4 * t + r)];
        }
        for (; j >= 4; j >>= 1) {            // cross-lane via shfl_xor
            int d = j >> 2;
            #pragma unroll
            for (int r = 0; r < 4; ++r) {
                int e = 4 * t + r;
                u64 mine = key[r];
                u64 part = __shfl_xor(mine, d, 64);
                bool up = ((e & k) == 0);
                bool lower = ((e & j) == 0);
                u64 mn = (mine < part) ? mine : part;
                u64 mx = (mine < part) ? part : mine;
                key[r] = (up == lower) ? mn : mx;
            }
        }
        for (; j >= 1; j >>= 1) {            // j in {2,1}: in-thread
            #pragma unroll
            for (int r = 0; r < 4; ++r) {
                int pr = r | j;
                if (((r & j) == 0) && pr < 4) {
                    int e = 4 * t + r;
                    bool up = ((e & k) == 0);
                    u64 a = key[r], cc = key[pr];
                    if ((a > cc) == up) { key[r] = cc; key[pr] = a; }
                }
            }
        }
    }

    __syncthreads();                         // sort arena dead; safe to alias

    // aliased post-sort LDS layout inside sm (bytes): h 0..18431,
    // crn_s 18432..26623, ha_s 26624..28671  (<= 40960)
    u64*    h_lds = sm;                      // [36][64] u64
    float4* crn_s = (float4*)(sm + 2304);    // [512]
    float*  ha_s  = (float*)(sm + 2304 + 1024); // [512]

    // ---- P2: corners epilogue ----
    #pragma unroll
    for (int r = 0; r < 4; ++r) {
        int e = 4 * t + r;
        u32 orig = (u32)key[r];
        const float* bp = in + (base + orig) * 5;
        float x = bp[1], y = bp[2], w = bp[3], h = bp[4];
        float ws_ = floorf(w * 0.5f);
        float hs_ = floorf(h * 0.5f);
        float4 c4 = make_float4(x - ws_, y - hs_, x + ws_, y + hs_);
        float hv = 0.5f * ((c4.z - c4.x) * (c4.w - c4.y));  // exact half-area
        size_t g = base + e;
        sortedIdx[g] = orig;
        crn[g] = c4;
        ha[g] = hv;
        if (e < 512) { crn_s[e] = c4; ha_s[e] = hv; }
    }
    for (int r = t; r < ROIS; r += 1024) kept[r] = 0;   // safety fallback
    __syncthreads();

    // ---- P3: h-block. unit u = tri(k,w) = k(k+1)/2+w, w<=k<8 ----
    for (int u = wid; u < 36; u += 16) {
        int kk = 0;
        while ((kk + 1) * (kk + 2) / 2 <= u) ++kk;
        int w = u - kk * (kk + 1) / 2;
        float4 myc = crn_s[64 * kk + lane];
        float  myh = ha_s[64 * kk + lane];
        u64 word = 0;
        #pragma unroll 4
        for (int q = 0; q < 64; ++q) {       // uniform -> LDS broadcast
            float4 rc = crn_s[64 * w + q];
            float  rh = ha_s[64 * w + q];
            bool p = sup_pred(rc, rh, myc, myh);
            word |= ((u64)(p ? 1u : 0u)) << q;
        }
        h_lds[(size_t)u * 64 + lane] = word;
    }
    __syncthreads();

    // ---- P4+P5: scan, wave 0 only (no barriers inside) ----
    if (t < 64) {
        int count = 0;
        u32 f[8];
        #pragma unroll
        for (int k = 0; k < 8; ++k) f[k] = 1u;

        bool done = false;
        #pragma unroll
        for (int g = 0; g < 8; ++g) {
            if (!done) {
                u64 hgg = h_lds[(size_t)(g * (g + 1) / 2 + g) * 64 + lane];
                u64 kb = 0;
                u64 avail = __ballot(f[g] != 0);
                while (avail != 0 && count < ROIS) {
                    int r = __builtin_ctzll(avail);      // wave-uniform
                    if (lane == 0) kept[count] = g * 64 + r;
                    ++count;
                    kb |= 1ULL << r;
                    u32 bit = (u32)(hgg >> r) & 1u;
                    f[g] &= (bit ^ 1u) & (u32)(lane != r);
                    avail = __ballot(f[g] != 0);
                }
                if (count >= ROIS) {
                    done = true;
                } else {
                    #pragma unroll
                    for (int k2 = g + 1; k2 < 8; ++k2)
                        f[k2] &= (u32)((h_lds[(size_t)(k2 * (k2 + 1) / 2 + g) * 64 + lane] & kb) == 0);
                }
            }
        }

        // ---- P5: generic tail (correctness path; input-dependent, rare) ----
        if (count < ROIS) {
            for (int Wp = 4; Wp < 32 && count < ROIS; ++Wp) {
                const int cLo = 128 * Wp + lane, cHi = cLo + 64;
                float4 cL = crn[base + cLo]; float hL = ha[base + cLo];
                float4 cH = crn[base + cHi]; float hH = ha[base + cHi];
                // suppression by all kept so far (positions in LDS kept[])
                u32 fLo = 1u, fHi = 1u;
                for (int j2 = 0; j2 < count; ++j2) {
                    int pos = kept[j2];
                    float4 kc = crn[base + pos]; float kh = ha[base + pos];
                    fLo &= (u32)(!sup_pred(kc, kh, cL, hL));
                    fHi &= (u32)(!sup_pred(kc, kh, cH, hH));
                }
                // in-window suppressor words (on-the-fly IoU)
                u64 curLo0 = 0, curHi0 = 0, curHi1 = 0;
                for (int r = 0; r < 64; ++r) {
                    float4 rc = crn[base + 128 * Wp + r]; float rh = ha[base + 128 * Wp + r];
                    curLo0 |= ((u64)(sup_pred(rc, rh, cL, hL) ? 1u : 0u)) << r;
                    curHi0 |= ((u64)(sup_pred(rc, rh, cH, hH) ? 1u : 0u)) << r;
                }
                for (int r = 0; r < 64; ++r) {
                    float4 rc = crn[base + 128 * Wp + 64 + r]; float rh = ha[base + 128 * Wp + 64 + r];
                    curHi1 |= ((u64)(sup_pred(rc, rh, cH, hH) ? 1u : 0u)) << r;
                }
                u64 availLo = __ballot(fLo != 0);
                while (availLo != 0 && count < ROIS) {
                    int r = __builtin_ctzll(availLo);
                    if (lane == 0) kept[count] = Wp * 128 + r;
                    ++count;
                    fLo &= (u32)(((curLo0 >> r) & 1ULL) ^ 1ULL) & (u32)(lane != r);
                    fHi &= (u32)(((curHi0 >> r) & 1ULL) ^ 1ULL);
                    availLo = __ballot(fLo != 0);
                }
                u64 availHi = __ballot(fHi != 0);
                while (availHi != 0 && count < ROIS) {
                    int r = __builtin_ctzll(availHi);
                    if (lane == 0) kept[count] = Wp * 128 + 64 + r;
                    ++count;
                    fHi &= (u32)(((curHi1 >> r) & 1ULL) ^ 1ULL) & (u32)(lane != r);
                    availHi = __ballot(fHi != 0);
                }
            }
        }
    }
    __syncthreads();

    // ---- P6: output gather ----
    if (t < ROIS) {
        int pos = kept[t];
        int orig = (int)sortedIdx[base + pos];
        const float* bp = in + (base + orig) * 5;
        ((float4*)outp)[(size_t)b * ROIS + t] =
            make_float4(bp[1], bp[2], bp[3], bp[4]);
    }
}

extern "C" void kernel_launch(void* const* d_in, const int* in_sizes, int n_in,
                              void* d_out, int out_size, void* d_ws, size_t ws_size,
                              hipStream_t stream) {
    const float* in = (const float*)d_in[0];
    float* out = (float*)d_out;
    char* ws = (char*)d_ws;

    u32* sortedIdx = (u32*)ws;                 size_t off = (size_t)NMS_B * NMS_N * 4;
    float4* crn = (float4*)(ws + off);         off += (size_t)NMS_B * NMS_N * 16;
    float* ha = (float*)(ws + off);            off += (size_t)NMS_B * NMS_N * 4;

    nms_all<<<NMS_B, 1024, 0, stream>>>(in, sortedIdx, crn, ha, out);
}

// Round 7
// 103.060 us; speedup vs baseline: 1.5143x; 1.2616x over previous
//
#include <hip/hip_runtime.h>
#include <stdint.h>

#pragma clang fp contract(off)

#define NMS_B 8
#define NMS_N 4096
#define ROIS 256

typedef unsigned long long u64;
typedef unsigned int u32;

__device__ __forceinline__ int lds_slot(int e) { return e + (e >> 2); }  // 4-way max bank aliasing

// suppression predicate (exact arithmetic of the proven K2):
// true => row box suppresses col box (IoU > 0.5); symmetric.
__device__ __forceinline__ bool sup_pred(float4 rc, float rh, float4 cc, float ch) {
    float iw = fmaxf(fminf(rc.z, cc.z) - fmaxf(rc.x, cc.x), 0.0f);
    float ih = fmaxf(fminf(rc.w, cc.w) - fmaxf(rc.y, cc.y), 0.0f);
    float inter = iw * ih;
    return inter > fmaf(-0.5f, inter, rh + ch);   // 1.5*inter > haR+haC
}

// ---------------------------------------------------------------------------
// v9: select-then-sort. v8 post-mortem: 81us kernel ~= 65us of 4096-bitonic
// (78 barriered stages on ONE CU/batch) + ~16us of useful work, while the
// scan only ever consumes the first ~512 sorted rows.
//  A: LDS histogram, bucket = floor(score*4096) (monotone in score).
//  B: threshold B = max{b : suffix>=512}; select bucket>=B (superset of the
//     exact top-512 under the (score desc, idx asc) key order; proof: the
//     512th element's bucket b* has suffix(b*)>=512 and suffix(b*+1)<512,
//     hence B<=b*). Append ~516 keys, pad to 1024 with ~0.
//  C: 1024-elem bitonic, 1 elem/thread (55 stages, LDS j>=64 / shfl j<=32)
//     -> first 512 sorted == bit-exact top-512 of the full sort.
//  D-F: v8's corners->LDS, 36-word h-block, wave-0 ballot scan, unchanged.
//  Fallback (uniform branch): full v8 path, for selCount>1024 or count<256
//  after 512 rows. Never runs on bench data; preserves exactness always.
// Fast path writes NOTHING global but the output.
// ---------------------------------------------------------------------------
__global__ __launch_bounds__(1024, 1) void nms_all(
        const float* __restrict__ in, u32* __restrict__ sortedIdx,
        float4* __restrict__ crn, float* __restrict__ ha,
        float* __restrict__ outp) {
    __shared__ u64 sm[5120];                 // 41 KB arena, phase-aliased
    __shared__ int kept[ROIS];
    __shared__ int s_selCount, s_B, s_needFull;
    const int b = blockIdx.x, t = threadIdx.x;
    const int lane = t & 63, wid = t >> 6;
    const size_t base = (size_t)b * NMS_N;

    // ---- Phase A: histogram ----
    u32* hist = (u32*)sm;                    // [4096] bytes 0..16383
    u32* pp   = (u32*)sm + 4096;             // [1024] bytes 16384..20479
    u32* qq   = (u32*)sm + 5120;             // [64]   bytes 20480..20735
    float sc[4];
    int   bk[4];
    #pragma unroll
    for (int r = 0; r < 4; ++r) {
        int e = t + 1024 * r;
        sc[r] = in[(base + e) * 5];
        int bb = (int)(sc[r] * 4096.0f);     // monotone; exact floor
        bk[r] = bb > 4095 ? 4095 : bb;
    }
    for (int i = t; i < 4096; i += 1024) hist[i] = 0;
    if (t == 0) { s_selCount = 0; s_needFull = 0; }
    __syncthreads();
    #pragma unroll
    for (int r = 0; r < 4; ++r) atomicAdd(&hist[bk[r]], 1u);
    __syncthreads();
    pp[t] = hist[4 * t] + hist[4 * t + 1] + hist[4 * t + 2] + hist[4 * t + 3];
    __syncthreads();
    if (t < 64) {
        u32 s = 0;
        for (int i = 0; i < 16; ++i) s += pp[16 * t + i];
        qq[t] = s;
    }
    __syncthreads();
    if (t == 0) {                            // hierarchical suffix search for B
        int acc = 0, L = 0;
        for (int l = 63; l >= 0; --l) { acc += (int)qq[l]; if (acc >= 512) { L = l; break; } }
        int rem = 512 - (acc - (int)qq[L]);
        int acc2 = 0, T = 16 * L;
        for (int i = 16 * L + 15; i >= 16 * L; --i) { acc2 += (int)pp[i]; if (acc2 >= rem) { T = i; break; } }
        int rem2 = rem - (acc2 - (int)pp[T]);
        int acc3 = 0, B = 4 * T;
        for (int bb = 4 * T + 3; bb >= 4 * T; --bb) { acc3 += (int)hist[bb]; if (acc3 >= rem2) { B = bb; break; } }
        s_B = B;
    }
    __syncthreads();

    // ---- Phase B: selection append (order-free: sort gives total order) ----
    u64* selKey = sm + 2560;                 // [1024] bytes 20480..28671 (qq dead)
    const int B = s_B;
    #pragma unroll
    for (int r = 0; r < 4; ++r) {
        if (bk[r] >= B) {
            int slot = atomicAdd(&s_selCount, 1);
            if (slot < 1024) {
                int e = t + 1024 * r;
                selKey[slot] = ((u64)(~__float_as_uint(sc[r])) << 32) | (u32)e;
            }
        }
    }
    __syncthreads();
    const int selCount = s_selCount;
    const bool fullPath = (selCount > 1024); // uniform

    if (!fullPath) {
        // ---- Phase C: bitonic sort of 1024, one element per thread ----
        u64 kk = (t < selCount) ? selKey[t] : ~0ULL;   // pad sorts to end
        for (int k = 2; k <= 1024; k <<= 1) {
            int j = k >> 1;
            for (; j >= 64; j >>= 1) {       // cross-wave via LDS (sm[0..1278])
                sm[lds_slot(t)] = kk;
                __syncthreads();
                u64 part = sm[lds_slot(t ^ j)];
                bool up = ((t & k) == 0), lower = ((t & j) == 0);
                u64 mn = kk < part ? kk : part, mx = kk < part ? part : kk;
                kk = (up == lower) ? mn : mx;
                __syncthreads();
            }
            for (; j >= 1; j >>= 1) {        // j<=32: in-wave shfl
                u64 part = __shfl_xor(kk, j, 64);
                bool up = ((t & k) == 0), lower = ((t & j) == 0);
                u64 mn = kk < part ? kk : part, mx = kk < part ? part : kk;
                kk = (up == lower) ? mn : mx;
            }
        }
        selKey[t] = kk;                      // sorted ascending
        __syncthreads();

        // ---- Phase D: corners for top 512 -> LDS ----
        float4* crn_s = (float4*)((char*)sm + 28672);  // [512] ..36863
        float*  ha_s  = (float*)((char*)sm + 36864);   // [512] ..38911
        u32*    sidx_s = (u32*)((char*)sm + 38912);    // [512] ..40959
        if (t < 512) {
            u32 orig = (u32)selKey[t];
            const float* bp = in + (base + orig) * 5;
            float x = bp[1], y = bp[2], w = bp[3], h = bp[4];
            float ws_ = floorf(w * 0.5f), hs_ = floorf(h * 0.5f);
            float4 c4 = make_float4(x - ws_, y - hs_, x + ws_, y + hs_);
            crn_s[t] = c4;
            ha_s[t] = 0.5f * ((c4.z - c4.x) * (c4.w - c4.y));  // exact half-area
            sidx_s[t] = orig;
        }
        for (int r = t; r < ROIS; r += 1024) kept[r] = 0;
        __syncthreads();

        // ---- Phase E: 36 lower-triangle suppressor words ----
        u64* h_lds = sm;                     // [36][64] bytes 0..18431
        for (int u = wid; u < 36; u += 16) {
            int kr = 0;
            while ((kr + 1) * (kr + 2) / 2 <= u) ++kr;
            int w = u - kr * (kr + 1) / 2;
            float4 myc = crn_s[64 * kr + lane];
            float  myh = ha_s[64 * kr + lane];
            u64 word = 0;
            #pragma unroll 4
            for (int q = 0; q < 64; ++q) {   // uniform -> LDS broadcast
                bool p = sup_pred(crn_s[64 * w + q], ha_s[64 * w + q], myc, myh);
                word |= ((u64)(p ? 1u : 0u)) << q;
            }
            h_lds[u * 64 + lane] = word;
        }
        __syncthreads();

        // ---- Phase F: ballot-chain scan, wave 0 ----
        if (t < 64) {
            int count = 0;
            u32 f[8];
            #pragma unroll
            for (int k = 0; k < 8; ++k) f[k] = 1u;
            bool done = false;
            #pragma unroll
            for (int g = 0; g < 8; ++g) {
                if (!done) {
                    u64 hgg = h_lds[(g * (g + 1) / 2 + g) * 64 + lane];
                    u64 kb = 0;
                    u64 avail = __ballot(f[g] != 0);
                    while (avail != 0 && count < ROIS) {
                        int r = __builtin_ctzll(avail);        // wave-uniform
                        if (lane == 0) kept[count] = g * 64 + r;
                        ++count;
                        kb |= 1ULL << r;
                        u32 bit = (u32)(hgg >> r) & 1u;
                        f[g] &= (bit ^ 1u) & (u32)(lane != r);
                        avail = __ballot(f[g] != 0);
                    }
                    if (count >= ROIS) {
                        done = true;
                    } else {
                        #pragma unroll
                        for (int k2 = g + 1; k2 < 8; ++k2)
                            f[k2] &= (u32)((h_lds[(k2 * (k2 + 1) / 2 + g) * 64 + lane] & kb) == 0);
                    }
                }
            }
            if (t == 0) s_needFull = (count >= ROIS) ? 0 : 1;
        }
        __syncthreads();
    }

    // ======== FULL FALLBACK (correctness-only; never on bench data) ========
    if (fullPath || s_needFull) {
        // P1: full 4096 bitonic sort (v8 verbatim)
        u64 key[4];
        #pragma unroll
        for (int r = 0; r < 4; ++r) {
            int e = 4 * t + r;
            float s = in[(base + e) * 5];
            key[r] = ((u64)(~__float_as_uint(s)) << 32) | (u32)e;
        }
        for (int k = 2; k <= 4096; k <<= 1) {
            int j = k >> 1;
            if (j >= 256) {
                #pragma unroll
                for (int r = 0; r < 4; ++r) sm[lds_slot(4 * t + r)] = key[r];
                __syncthreads();
                for (; j >= 256; j >>= 1) {
                    for (int el = t; el < 4096; el += 1024) {
                        int p = el ^ j;
                        if (p > el) {
                            u64 a = sm[lds_slot(el)], cc = sm[lds_slot(p)];
                            bool up = ((el & k) == 0);
                            if ((a > cc) == up) { sm[lds_slot(el)] = cc; sm[lds_slot(p)] = a; }
                        }
                    }
                    __syncthreads();
                }
                #pragma unroll
                for (int r = 0; r < 4; ++r) key[r] = sm[lds_slot(4 * t + r)];
            }
            for (; j >= 4; j >>= 1) {
                int d = j >> 2;
                #pragma unroll
                for (int r = 0; r < 4; ++r) {
                    int e = 4 * t + r;
                    u64 mine = key[r];
                    u64 part = __shfl_xor(mine, d, 64);
                    bool up = ((e & k) == 0);
                    bool lower = ((e & j) == 0);
                    u64 mn = (mine < part) ? mine : part;
                    u64 mx = (mine < part) ? part : mine;
                    key[r] = (up == lower) ? mn : mx;
                }
            }
            for (; j >= 1; j >>= 1) {
                #pragma unroll
                for (int r = 0; r < 4; ++r) {
                    int pr = r | j;
                    if (((r & j) == 0) && pr < 4) {
                        int e = 4 * t + r;
                        bool up = ((e & k) == 0);
                        u64 a = key[r], cc = key[pr];
                        if ((a > cc) == up) { key[r] = cc; key[pr] = a; }
                    }
                }
            }
        }
        __syncthreads();

        u64*    h2 = sm;                      // [36][64]
        float4* crn2 = (float4*)(sm + 2304);  // [512]
        float*  ha2  = (float*)(sm + 2304 + 1024);

        // P2
        #pragma unroll
        for (int r = 0; r < 4; ++r) {
            int e = 4 * t + r;
            u32 orig = (u32)key[r];
            const float* bp = in + (base + orig) * 5;
            float x = bp[1], y = bp[2], w = bp[3], h = bp[4];
            float ws_ = floorf(w * 0.5f), hs_ = floorf(h * 0.5f);
            float4 c4 = make_float4(x - ws_, y - hs_, x + ws_, y + hs_);
            float hv = 0.5f * ((c4.z - c4.x) * (c4.w - c4.y));
            size_t g = base + e;
            sortedIdx[g] = orig;
            crn[g] = c4;
            ha[g] = hv;
            if (e < 512) { crn2[e] = c4; ha2[e] = hv; }
        }
        for (int r = t; r < ROIS; r += 1024) kept[r] = 0;
        __syncthreads();

        // P3
        for (int u = wid; u < 36; u += 16) {
            int kr = 0;
            while ((kr + 1) * (kr + 2) / 2 <= u) ++kr;
            int w = u - kr * (kr + 1) / 2;
            float4 myc = crn2[64 * kr + lane];
            float  myh = ha2[64 * kr + lane];
            u64 word = 0;
            #pragma unroll 4
            for (int q = 0; q < 64; ++q) {
                bool p = sup_pred(crn2[64 * w + q], ha2[64 * w + q], myc, myh);
                word |= ((u64)(p ? 1u : 0u)) << q;
            }
            h2[(size_t)u * 64 + lane] = word;
        }
        __syncthreads();

        // P4+P5
        if (t < 64) {
            int count = 0;
            u32 f[8];
            #pragma unroll
            for (int k = 0; k < 8; ++k) f[k] = 1u;
            bool done = false;
            #pragma unroll
            for (int g = 0; g < 8; ++g) {
                if (!done) {
                    u64 hgg = h2[(size_t)(g * (g + 1) / 2 + g) * 64 + lane];
                    u64 kb = 0;
                    u64 avail = __ballot(f[g] != 0);
                    while (avail != 0 && count < ROIS) {
                        int r = __builtin_ctzll(avail);
                        if (lane == 0) kept[count] = g * 64 + r;
                        ++count;
                        kb |= 1ULL << r;
                        u32 bit = (u32)(hgg >> r) & 1u;
                        f[g] &= (bit ^ 1u) & (u32)(lane != r);
                        avail = __ballot(f[g] != 0);
                    }
                    if (count >= ROIS) {
                        done = true;
                    } else {
                        #pragma unroll
                        for (int k2 = g + 1; k2 < 8; ++k2)
                            f[k2] &= (u32)((h2[(size_t)(k2 * (k2 + 1) / 2 + g) * 64 + lane] & kb) == 0);
                    }
                }
            }
            if (count < ROIS) {
                for (int Wp = 4; Wp < 32 && count < ROIS; ++Wp) {
                    const int cLo = 128 * Wp + lane, cHi = cLo + 64;
                    float4 cL = crn[base + cLo]; float hL = ha[base + cLo];
                    float4 cH = crn[base + cHi]; float hH = ha[base + cHi];
                    u32 fLo = 1u, fHi = 1u;
                    for (int j2 = 0; j2 < count; ++j2) {
                        int pos = kept[j2];
                        float4 kc = crn[base + pos]; float kh = ha[base + pos];
                        fLo &= (u32)(!sup_pred(kc, kh, cL, hL));
                        fHi &= (u32)(!sup_pred(kc, kh, cH, hH));
                    }
                    u64 curLo0 = 0, curHi0 = 0, curHi1 = 0;
                    for (int r = 0; r < 64; ++r) {
                        float4 rc = crn[base + 128 * Wp + r]; float rh = ha[base + 128 * Wp + r];
                        curLo0 |= ((u64)(sup_pred(rc, rh, cL, hL) ? 1u : 0u)) << r;
                        curHi0 |= ((u64)(sup_pred(rc, rh, cH, hH) ? 1u : 0u)) << r;
                    }
                    for (int r = 0; r < 64; ++r) {
                        float4 rc = crn[base + 128 * Wp + 64 + r]; float rh = ha[base + 128 * Wp + 64 + r];
                        curHi1 |= ((u64)(sup_pred(rc, rh, cH, hH) ? 1u : 0u)) << r;
                    }
                    u64 availLo = __ballot(fLo != 0);
                    while (availLo != 0 && count < ROIS) {
                        int r = __builtin_ctzll(availLo);
                        if (lane == 0) kept[count] = Wp * 128 + r;
                        ++count;
                        fLo &= (u32)(((curLo0 >> r) & 1ULL) ^ 1ULL) & (u32)(lane != r);
                        fHi &= (u32)(((curHi0 >> r) & 1ULL) ^ 1ULL);
                        availLo = __ballot(fLo != 0);
                    }
                    u64 availHi = __ballot(fHi != 0);
                    while (availHi != 0 && count < ROIS) {
                        int r = __builtin_ctzll(availHi);
                        if (lane == 0) kept[count] = Wp * 128 + 64 + r;
                        ++count;
                        fHi &= (u32)(((curHi1 >> r) & 1ULL) ^ 1ULL) & (u32)(lane != r);
                        availHi = __ballot(fHi != 0);
                    }
                }
            }
        }
    }
    __syncthreads();

    // ---- output ----
    const bool usedFull = fullPath || (s_needFull != 0);
    if (t < ROIS) {
        int pos = kept[t];
        int orig = usedFull ? (int)sortedIdx[base + pos]
                            : (int)((u32*)((char*)sm + 38912))[pos];
        const float* bp = in + (base + orig) * 5;
        ((float4*)outp)[(size_t)b * ROIS + t] =
            make_float4(bp[1], bp[2], bp[3], bp[4]);
    }
}

extern "C" void kernel_launch(void* const* d_in, const int* in_sizes, int n_in,
                              void* d_out, int out_size, void* d_ws, size_t ws_size,
                              hipStream_t stream) {
    const float* in = (const float*)d_in[0];
    float* out = (float*)d_out;
    char* ws = (char*)d_ws;

    u32* sortedIdx = (u32*)ws;                 size_t off = (size_t)NMS_B * NMS_N * 4;
    float4* crn = (float4*)(ws + off);         off += (size_t)NMS_B * NMS_N * 16;
    float* ha = (float*)(ws + off);            off += (size_t)NMS_B * NMS_N * 4;

    nms_all<<<NMS_B, 1024, 0, stream>>>(in, sortedIdx, crn, ha, out);
}